// Round 8
// baseline (2516.717 us; speedup 1.0000x reference)
//
#include <hip/hip_runtime.h>
#include <hip/hip_bf16.h>

#define HIDDEN   1024
#define XDIM     130
#define CONDDIM  44
#define INDIM    174      // XDIM + CONDDIM
#define NSTEP    16
#define BP       4096     // effective batch (64*64)
#define K0P      1088     // 1024 (h0) + 44 (y) + 20 pad  -> 34 K-tiles of 32
#define K1P      2048     // 1024 (h0') + 1024 (h1)       -> 64 K-tiles of 32
#define GN       4096     // 4*HIDDEN gate dim
#define LGN      256      // padded logits cols (130 -> 256)

typedef __bf16 bf16x8 __attribute__((ext_vector_type(8)));
typedef float  f32x4  __attribute__((ext_vector_type(4)));

// fused gate column order: n in [0,4096) -> q=(n>>4)&3 (gate), j=((n>>6)<<4)|(n&15)
__device__ __forceinline__ int fused_row(int n) {
  const int q = (n >> 4) & 3;
  const int j = ((n >> 6) << 4) | (n & 15);
  return q * HIDDEN + j;
}

// ---------------------------------------------------------------- helpers
__device__ __forceinline__ void g2lds16(const void* g, void* l) {
  __builtin_amdgcn_global_load_lds(
      (const __attribute__((address_space(1))) void*)g,
      (__attribute__((address_space(3))) void*)l, 16, 0, 0);
}

__device__ __forceinline__ float sigm(float x)  { return 1.f / (1.f + __expf(-x)); }
__device__ __forceinline__ float tanhfast(float x) { return 2.f / (1.f + __expf(-2.f * x)) - 1.f; }

// ---------------------------------------------------------------- 256^2 pipelined GEMM + LSTM cell
// (R4 variant — fastest measured: 78 µs @ K=2048, 0 bank conflicts)
// 8 waves (2M x 4N), BK=32, 4 LDS buffers, 3-ahead prefetch, counted vmcnt.
// T2 swizzle: 16B k-slot XORed with ((row>>1)&3); LDS dest linear,
// global SOURCE pre-XORed per lane, every ds_read applies the same XOR.
template<bool FB>
__global__ __launch_bounds__(512, 2)
void gemm256_cell_k(const __hip_bfloat16* __restrict__ A,
                    const __hip_bfloat16* __restrict__ W, int K,
                    const float* __restrict__ bcomb,     // 4096, fused order
                    const float* __restrict__ W0T,       // 130 x 4096 fused order (FB only)
                    const int*   __restrict__ idx,       // per-row feedback index (FB only)
                    float* __restrict__ c,
                    __hip_bfloat16* __restrict__ h1dst, int ld1,
                    __hip_bfloat16* __restrict__ h2dst, int ld2)
{
  // 4 buffers x (A 256x32 + B 256x32) bf16 = 4 x 32 KB = 128 KB
  __shared__ __align__(16) __hip_bfloat16 lds[4 * 16384];

  const int tid  = threadIdx.x;
  const int w    = tid >> 6;        // wave 0..7
  const int lane = tid & 63;
  const int bid  = blockIdx.x;      // 256 blocks
  const int swz  = ((bid & 7) << 5) | (bid >> 3);   // XCD-chunked (256 % 8 == 0)
  const int m0   = (swz >> 4) * 256;
  const int n0   = (swz & 15) * 256;
  const int wm   = w >> 2;          // 0..1 : row half
  const int wn   = w & 3;           // 0..3 : col quarter
  const int fr   = lane & 15;
  // swizzled fragment k offset: slot' = (lane>>4) ^ ((fr>>1)&3)  (row bases are x16)
  const int kqs  = (((lane >> 4) ^ ((fr >> 1) & 3)) * 8);
  const int sr   = lane >> 2;       // staging row within 16-row issue
  // pre-swizzled SOURCE col offset: slot' = (lane&3) ^ ((sr>>1)&3)  (elements)
  const int sc   = (((lane & 3) ^ ((sr >> 1) & 3)) * 8);
  const int NT   = K >> 5;

  f32x4 acc[8][4] = {};

  // --- staging: one wave-issue = 16 rows x 64B = 1 KB; 2 issues each for A and B ---
  #define STAGE_A(t, d, i)                                                          \
    g2lds16(A + (size_t)(m0 + w * 32 + (i) * 16 + sr) * K + ((t) * 32 + sc),        \
            (void*)(lds + (d) * 16384 + w * 1024 + (i) * 512))
  #define STAGE_B(t, d, i)                                                          \
    g2lds16(W + (size_t)(n0 + w * 32 + (i) * 16 + sr) * K + ((t) * 32 + sc),        \
            (void*)(lds + (d) * 16384 + 8192 + w * 1024 + (i) * 512))

  // prologue: stage tiles 0,1,2 into buffers 0,1,2
  const int npro = (NT < 3) ? NT : 3;
  for (int t = 0; t < npro; ++t) {
    STAGE_A(t, t, 0); STAGE_B(t, t, 0);
    STAGE_A(t, t, 1); STAGE_B(t, t, 1);
  }
  if (NT >= 3)      asm volatile("s_waitcnt vmcnt(8)" ::: "memory");
  else if (NT == 2) asm volatile("s_waitcnt vmcnt(4)" ::: "memory");
  else              asm volatile("s_waitcnt vmcnt(0)" ::: "memory");
  __builtin_amdgcn_s_barrier();

  for (int t = 0; t < NT; ++t) {
    const int d  = t & 3;
    const __hip_bfloat16* As = lds + d * 16384;
    const __hip_bfloat16* Bs = As + 8192;
    const int tp = t + 3;
    const int dp = tp & 3;
    const bool pf = tp < NT;

    bf16x8 bfr[4];
    #pragma unroll
    for (int nf = 0; nf < 4; ++nf)
      bfr[nf] = *reinterpret_cast<const bf16x8*>(&Bs[(wn * 64 + nf * 16 + fr) * 32 + kqs]);

    #pragma unroll
    for (int half = 0; half < 2; ++half) {
      if (pf) {
        if (half == 0) { STAGE_A(tp, dp, 0); STAGE_A(tp, dp, 1); }
        else           { STAGE_B(tp, dp, 0); STAGE_B(tp, dp, 1); }
      }
      bf16x8 afr[4];
      #pragma unroll
      for (int q = 0; q < 4; ++q)
        afr[q] = *reinterpret_cast<const bf16x8*>(&As[(wm * 128 + (half * 4 + q) * 16 + fr) * 32 + kqs]);
      __builtin_amdgcn_s_setprio(1);
      #pragma unroll
      for (int q = 0; q < 4; ++q)
        #pragma unroll
        for (int nf = 0; nf < 4; ++nf)
          acc[half * 4 + q][nf] =
              __builtin_amdgcn_mfma_f32_16x16x32_bf16(afr[q], bfr[nf], acc[half * 4 + q][nf], 0, 0, 0);
      __builtin_amdgcn_s_setprio(0);
    }

    // wait tile t+1 landed; keep up to 2 younger tiles in flight (never vmcnt(0) mid-loop)
    if (t + 3 < NT)      asm volatile("s_waitcnt vmcnt(8)" ::: "memory");
    else if (t + 2 < NT) asm volatile("s_waitcnt vmcnt(4)" ::: "memory");
    else if (t + 1 < NT) asm volatile("s_waitcnt vmcnt(0)" ::: "memory");
    if (t + 1 < NT) __builtin_amdgcn_s_barrier();
  }
  #undef STAGE_A
  #undef STAGE_B

  // ---- fused LSTM cell epilogue ----
  const int fq = lane >> 4;
  const int cb = n0 + wn * 64;            // quadrant col base (multiple of 64)
  const int j  = ((cb >> 6) << 4) | fr;   // this lane's hidden index

  const float bs0 = bcomb[cb + fr];
  const float bs1 = bcomb[cb + 16 + fr];
  const float bs2 = bcomb[cb + 32 + fr];
  const float bs3 = bcomb[cb + 48 + fr];

  #pragma unroll
  for (int mf = 0; mf < 8; ++mf) {
    #pragma unroll
    for (int r = 0; r < 4; ++r) {
      const int b = m0 + wm * 128 + mf * 16 + fq * 4 + r;
      float gi = acc[mf][0][r] + bs0;
      float gf = acc[mf][1][r] + bs1;
      float gg = acc[mf][2][r] + bs2;
      float go = acc[mf][3][r] + bs3;
      if (FB) {
        const float* wr = W0T + (size_t)idx[b] * GN;
        gi += wr[cb + fr];
        gf += wr[cb + 16 + fr];
        gg += wr[cb + 32 + fr];
        go += wr[cb + 48 + fr];
      }
      const size_t ci = (size_t)b * HIDDEN + j;
      const float cn = sigm(gf) * c[ci] + sigm(gi) * tanhfast(gg);
      c[ci] = cn;
      const float hn = sigm(go) * tanhfast(cn);
      const __hip_bfloat16 hb = __float2bfloat16(hn);
      h1dst[(size_t)b * ld1 + j] = hb;
      if (h2dst) h2dst[(size_t)b * ld2 + j] = hb;
    }
  }
}

// ---------------------------------------------------------------- fused logits GEMM + log_softmax + argmax + y staging
// 32 rows x 256 cols per block, K = HIDDEN, grid 128 blocks, 4 waves (1M x 4N).
// After the K-loop: acc -> LDS [32][256] f32, per-row max/argmax/lse, write logp
// directly to out, idx for feedback, and next step's y slice into A0next.
__global__ __launch_bounds__(256, 4)
void logsm_k(const __hip_bfloat16* __restrict__ A, int lda,   // h1' rows, lda = K1P
             const __hip_bfloat16* __restrict__ Wfp,          // [256][1024] bf16
             const float* __restrict__ bfv,                   // bf (130)
             float* __restrict__ out, int t,
             const float* __restrict__ x,
             __hip_bfloat16* __restrict__ A0next,
             int* __restrict__ idx)
{
  // As [32][32] bf16 (2 KB) + Bs [256][32] bf16 (16 KB) during GEMM;
  // reused afterwards as SC [32][256] f32 (32 KB) + row stats.
  __shared__ __align__(16) char smem[33280];
  __hip_bfloat16* As = (__hip_bfloat16*)smem;
  __hip_bfloat16* Bs = (__hip_bfloat16*)(smem + 2048);
  float* SC = (float*)smem;                 // [32][256]
  float* RM = (float*)(smem + 32768);       // [32] row max
  float* RL = (float*)(smem + 32768 + 128); // [32] row lse

  const int tid  = threadIdx.x;
  const int w    = tid >> 6;        // wave 0..3 (n-quadrant)
  const int lane = tid & 63;
  const int m0   = blockIdx.x * 32;
  const int fr   = lane & 15;
  const int kqs  = (((lane >> 4) ^ ((fr >> 1) & 3)) * 8);
  const int sr   = lane >> 2;
  const int sc   = (((lane & 3) ^ ((sr >> 1) & 3)) * 8);

  f32x4 acc[2][4] = {};

  for (int k0 = 0; k0 < HIDDEN; k0 += 32) {
    __syncthreads();
    if (w < 2)   // A: 2 stripes of 16 rows
      g2lds16(A + (size_t)(m0 + w * 16 + sr) * lda + (k0 + sc), (void*)(As + (w * 16) * 32));
    #pragma unroll
    for (int i = 0; i < 4; ++i)   // B: each wave stages its 64-row group
      g2lds16(Wfp + (size_t)(w * 64 + i * 16 + sr) * HIDDEN + (k0 + sc),
              (void*)(Bs + (w * 64 + i * 16) * 32));
    __syncthreads();

    bf16x8 af[2], bw[4];
    #pragma unroll
    for (int i = 0; i < 2; ++i)
      af[i] = *reinterpret_cast<const bf16x8*>(&As[(i * 16 + fr) * 32 + kqs]);
    #pragma unroll
    for (int j = 0; j < 4; ++j)
      bw[j] = *reinterpret_cast<const bf16x8*>(&Bs[(w * 64 + j * 16 + fr) * 32 + kqs]);
    #pragma unroll
    for (int i = 0; i < 2; ++i)
      #pragma unroll
      for (int j = 0; j < 4; ++j)
        acc[i][j] = __builtin_amdgcn_mfma_f32_16x16x32_bf16(af[i], bw[j], acc[i][j], 0, 0, 0);
  }

  __syncthreads();   // done with As/Bs; reuse as SC
  const int fq = lane >> 4;
  #pragma unroll
  for (int i = 0; i < 2; ++i)
    #pragma unroll
    for (int j = 0; j < 4; ++j)
      #pragma unroll
      for (int r = 0; r < 4; ++r)
        SC[(i * 16 + fq * 4 + r) * 256 + w * 64 + j * 16 + fr] = acc[i][j][r];
  __syncthreads();

  if (tid < 32) {
    const int r = tid;
    const float* row = SC + r * 256;
    float m = -__builtin_inff();
    int bi = 0;
    for (int cI = 0; cI < XDIM; ++cI) {
      const float v = row[cI] + bfv[cI];
      if (v > m) { m = v; bi = cI; }          // strict > keeps first argmax
    }
    float s = 0.f;
    for (int cI = 0; cI < XDIM; ++cI)
      s += __expf(row[cI] + bfv[cI] - m);
    RM[r] = m;
    RL[r] = __logf(s);
    idx[m0 + r] = bi;
  }
  __syncthreads();

  for (int e = tid; e < 32 * XDIM; e += 256) {
    const int r = e / XDIM, cI = e - r * XDIM;
    out[((size_t)(m0 + r) * NSTEP + t) * XDIM + cI] =
        SC[r * 256 + cI] + bfv[cI] - RM[r] - RL[r];
  }

  if (t + 1 < NSTEP) {   // stage next step's y (+ zero pad) into A0next cols 1024..1087
    for (int e = tid; e < 32 * 64; e += 256) {
      const int r = e >> 6, s2 = e & 63;
      const float yv = (s2 < CONDDIM)
          ? x[((size_t)(m0 + r) * NSTEP + (t + 1)) * INDIM + XDIM + s2] : 0.f;
      A0next[(size_t)(m0 + r) * K0P + HIDDEN + s2] = __float2bfloat16(yv);
    }
  }
}

// ---------------------------------------------------------------- init + weight packing
__global__ void init_k(const float* __restrict__ z, const float* __restrict__ x,
                       float* __restrict__ c0, float* __restrict__ c1,
                       __hip_bfloat16* __restrict__ A0, __hip_bfloat16* __restrict__ A1,
                       int* __restrict__ idx)
{
  const int t = blockIdx.x * blockDim.x + threadIdx.x;
  if (t >= BP * K1P) return;
  const int b = t >> 11;
  const int j = t & 2047;
  if (j >= HIDDEN)   // A1 second half: h1(-1) = z
    A1[(size_t)b * K1P + j] = __float2bfloat16(z[(size_t)b * HIDDEN + (j - HIDDEN)]);
  if (j < HIDDEN) {
    c0[(size_t)b * HIDDEN + j] = 0.f;
    c1[(size_t)b * HIDDEN + j] = 0.f;
    A0[(size_t)b * K0P + j] = __float2bfloat16(z[(size_t)b * HIDDEN + j]);  // h0(-1) = z
  } else if (j < HIDDEN + 64) {                     // y_0 + zero pad
    const int k = j - HIDDEN;
    const float yv = (k < CONDDIM) ? x[((size_t)b * NSTEP) * INDIM + XDIM + k] : 0.f;
    A0[(size_t)b * K0P + j] = __float2bfloat16(yv);
  }
  if (j == 0) idx[b] = 1;   // o0 one-hot at index 1
}

__global__ void pack0_k(const float* __restrict__ Wih0, const float* __restrict__ Whh0,
                        const float* __restrict__ bih0, const float* __restrict__ bhh0,
                        __hip_bfloat16* __restrict__ Wc0, float* __restrict__ bc0)
{
  const int t = blockIdx.x * blockDim.x + threadIdx.x;
  if (t >= GN * K0P) return;
  const int n = t / K0P, k = t % K0P;
  const int row = fused_row(n);
  float v = 0.f;
  if (k < HIDDEN)                v = Whh0[(size_t)row * HIDDEN + k];
  else if (k < HIDDEN + CONDDIM) v = Wih0[(size_t)row * INDIM + XDIM + (k - HIDDEN)];
  Wc0[t] = __float2bfloat16(v);
  if (k == 0) bc0[n] = bih0[row] + bhh0[row];
}

__global__ void pack1_k(const float* __restrict__ Wih1, const float* __restrict__ Whh1,
                        const float* __restrict__ bih1, const float* __restrict__ bhh1,
                        __hip_bfloat16* __restrict__ Wc1, float* __restrict__ bc1)
{
  const int t = blockIdx.x * blockDim.x + threadIdx.x;
  if (t >= GN * K1P) return;
  const int n = t >> 11, k = t & 2047;
  const int row = fused_row(n);
  const float v = (k < HIDDEN) ? Wih1[(size_t)row * HIDDEN + k]
                               : Whh1[(size_t)row * HIDDEN + (k - HIDDEN)];
  Wc1[t] = __float2bfloat16(v);
  if (k == 0) bc1[n] = bih1[row] + bhh1[row];
}

__global__ void packf_k(const float* __restrict__ Wf, __hip_bfloat16* __restrict__ Wfp)
{
  const int t = blockIdx.x * blockDim.x + threadIdx.x;
  if (t >= LGN * HIDDEN) return;
  const int r = t >> 10, k = t & 1023;
  const float v = (r < XDIM) ? Wf[(size_t)r * HIDDEN + k] : 0.f;
  Wfp[t] = __float2bfloat16(v);
}

__global__ void packt_k(const float* __restrict__ Wih0, float* __restrict__ W0T)
{
  const int t = blockIdx.x * blockDim.x + threadIdx.x;
  if (t >= XDIM * GN) return;
  const int e = t >> 12, n = t & 4095;      // W0T[e][n] = Wih0[fused_row(n)][e]
  W0T[t] = Wih0[(size_t)fused_row(n) * INDIM + e];
}

// ---------------------------------------------------------------- launch
extern "C" void kernel_launch(void* const* d_in, const int* in_sizes, int n_in,
                              void* d_out, int out_size, void* d_ws, size_t ws_size,
                              hipStream_t stream)
{
  const float* z    = (const float*)d_in[0];
  const float* x    = (const float*)d_in[1];
  const float* Wih0 = (const float*)d_in[2];
  const float* Whh0 = (const float*)d_in[3];
  const float* bih0 = (const float*)d_in[4];
  const float* bhh0 = (const float*)d_in[5];
  const float* Wih1 = (const float*)d_in[6];
  const float* Whh1 = (const float*)d_in[7];
  const float* bih1 = (const float*)d_in[8];
  const float* bhh1 = (const float*)d_in[9];
  const float* Wf   = (const float*)d_in[10];
  const float* bfv  = (const float*)d_in[11];
  float* out = (float*)d_out;

  char* ws = (char*)d_ws;
  size_t off = 0;
  auto alloc = [&](size_t bytes) { void* p = ws + off; off += (bytes + 255) & ~(size_t)255; return p; };

  __hip_bfloat16* A0a = (__hip_bfloat16*)alloc((size_t)BP * K0P * 2);
  __hip_bfloat16* A0b = (__hip_bfloat16*)alloc((size_t)BP * K0P * 2);
  __hip_bfloat16* A1a = (__hip_bfloat16*)alloc((size_t)BP * K1P * 2);
  __hip_bfloat16* A1b = (__hip_bfloat16*)alloc((size_t)BP * K1P * 2);
  __hip_bfloat16* Wc0 = (__hip_bfloat16*)alloc((size_t)GN * K0P * 2);
  __hip_bfloat16* Wc1 = (__hip_bfloat16*)alloc((size_t)GN * K1P * 2);
  __hip_bfloat16* Wfp = (__hip_bfloat16*)alloc((size_t)LGN * HIDDEN * 2);
  float*          W0T = (float*)         alloc((size_t)XDIM * GN * 4);
  float*          bc0 = (float*)         alloc((size_t)GN * 4);
  float*          bc1 = (float*)         alloc((size_t)GN * 4);
  float*          c0  = (float*)         alloc((size_t)BP * HIDDEN * 4);
  float*          c1  = (float*)         alloc((size_t)BP * HIDDEN * 4);
  int*            idx = (int*)           alloc((size_t)BP * 4);
  (void)ws_size; (void)in_sizes; (void)n_in; (void)out_size;

  pack0_k<<<(GN * K0P + 255) / 256, 256, 0, stream>>>(Wih0, Whh0, bih0, bhh0, Wc0, bc0);
  pack1_k<<<(GN * K1P + 255) / 256, 256, 0, stream>>>(Wih1, Whh1, bih1, bhh1, Wc1, bc1);
  packf_k<<<(LGN * HIDDEN + 255) / 256, 256, 0, stream>>>(Wf, Wfp);
  packt_k<<<(XDIM * GN + 255) / 256, 256, 0, stream>>>(Wih0, W0T);
  init_k<<<(BP * K1P + 255) / 256, 256, 0, stream>>>(z, x, c0, c1, A0a, A1a, idx);

  for (int t = 0; t < NSTEP; ++t) {
    __hip_bfloat16* A0c = (t & 1) ? A0b : A0a;
    __hip_bfloat16* A0n = (t & 1) ? A0a : A0b;
    __hip_bfloat16* A1c = (t & 1) ? A1b : A1a;
    __hip_bfloat16* A1n = (t & 1) ? A1a : A1b;

    // layer 0: gates = [h0|y] @ [Whh0|Wih0_y]^T, fused cell -> h0'
    gemm256_cell_k<true><<<256, 512, 0, stream>>>(
        A0c, Wc0, K0P, bc0, W0T, idx, c0,
        A1c, K1P,        // h0' -> A1 (current) first half, read by GEMM1 this step
        A0n, K0P);       // h0' -> A0 (next step)
    // layer 1: gates = [h0'|h1] @ [Wih1|Whh1]^T, fused cell -> h1'
    gemm256_cell_k<false><<<256, 512, 0, stream>>>(
        A1c, Wc1, K1P, bc1, nullptr, nullptr, c1,
        A1n + HIDDEN, K1P,   // h1' -> A1 (next) second half
        nullptr, 0);
    // logits = h1' @ Wf^T fused with log_softmax/argmax/y-staging
    logsm_k<<<128, 256, 0, stream>>>(
        A1n + HIDDEN, K1P, Wfp, bfv, out, t, x, A0n, idx);
  }
}

// Round 9
// 2343.087 us; speedup vs baseline: 1.0741x; 1.0741x over previous
//
#include <hip/hip_runtime.h>
#include <hip/hip_bf16.h>

#define HIDDEN   1024
#define XDIM     130
#define CONDDIM  44
#define INDIM    174      // XDIM + CONDDIM
#define NSTEP    16
#define BP       4096     // effective batch (64*64)
#define K0P      1088     // 1024 (h0) + 44 (y) + 20 pad  -> 34 K-tiles of 32
#define K1P      2048     // 1024 (h0') + 1024 (h1)       -> 64 K-tiles of 32
#define GN       4096     // 4*HIDDEN gate dim
#define LGN      256      // padded logits cols (130 -> 256)

typedef __bf16 bf16x8 __attribute__((ext_vector_type(8)));
typedef float  f32x4  __attribute__((ext_vector_type(4)));

// fused gate column order: n in [0,4096) -> q=(n>>4)&3 (gate), j=((n>>6)<<4)|(n&15)
__device__ __forceinline__ int fused_row(int n) {
  const int q = (n >> 4) & 3;
  const int j = ((n >> 6) << 4) | (n & 15);
  return q * HIDDEN + j;
}

// ---------------------------------------------------------------- helpers
__device__ __forceinline__ void g2lds16(const void* g, void* l) {
  __builtin_amdgcn_global_load_lds(
      (const __attribute__((address_space(1))) void*)g,
      (__attribute__((address_space(3))) void*)l, 16, 0, 0);
}

__device__ __forceinline__ float sigm(float x)  { return 1.f / (1.f + __expf(-x)); }
__device__ __forceinline__ float tanhfast(float x) { return 2.f / (1.f + __expf(-2.f * x)) - 1.f; }

// ---------------------------------------------------------------- 256^2 pipelined GEMM + LSTM cell
// (R4 variant — fastest measured: 78 µs @ K=2048, 0 bank conflicts)
// 8 waves (2M x 4N), BK=32, 4 LDS buffers, 3-ahead prefetch, counted vmcnt.
// T2 swizzle: 16B k-slot XORed with ((row>>1)&3); LDS dest linear,
// global SOURCE pre-XORed per lane, every ds_read applies the same XOR.
template<bool FB>
__global__ __launch_bounds__(512, 2)
void gemm256_cell_k(const __hip_bfloat16* __restrict__ A,
                    const __hip_bfloat16* __restrict__ W, int K,
                    const float* __restrict__ bcomb,     // 4096, fused order
                    const float* __restrict__ W0T,       // 130 x 4096 fused order (FB only)
                    const int*   __restrict__ idx,       // per-row feedback index (FB only)
                    float* __restrict__ c,
                    __hip_bfloat16* __restrict__ h1dst, int ld1,
                    __hip_bfloat16* __restrict__ h2dst, int ld2)
{
  // 4 buffers x (A 256x32 + B 256x32) bf16 = 4 x 32 KB = 128 KB
  __shared__ __align__(16) __hip_bfloat16 lds[4 * 16384];

  const int tid  = threadIdx.x;
  const int w    = tid >> 6;        // wave 0..7
  const int lane = tid & 63;
  const int bid  = blockIdx.x;      // 256 blocks
  const int swz  = ((bid & 7) << 5) | (bid >> 3);   // XCD-chunked (256 % 8 == 0)
  const int m0   = (swz >> 4) * 256;
  const int n0   = (swz & 15) * 256;
  const int wm   = w >> 2;          // 0..1 : row half
  const int wn   = w & 3;           // 0..3 : col quarter
  const int fr   = lane & 15;
  // swizzled fragment k offset: slot' = (lane>>4) ^ ((fr>>1)&3)  (row bases are x16)
  const int kqs  = (((lane >> 4) ^ ((fr >> 1) & 3)) * 8);
  const int sr   = lane >> 2;       // staging row within 16-row issue
  // pre-swizzled SOURCE col offset: slot' = (lane&3) ^ ((sr>>1)&3)  (elements)
  const int sc   = (((lane & 3) ^ ((sr >> 1) & 3)) * 8);
  const int NT   = K >> 5;

  f32x4 acc[8][4] = {};

  // --- staging: one wave-issue = 16 rows x 64B = 1 KB; 2 issues each for A and B ---
  #define STAGE_A(t, d, i)                                                          \
    g2lds16(A + (size_t)(m0 + w * 32 + (i) * 16 + sr) * K + ((t) * 32 + sc),        \
            (void*)(lds + (d) * 16384 + w * 1024 + (i) * 512))
  #define STAGE_B(t, d, i)                                                          \
    g2lds16(W + (size_t)(n0 + w * 32 + (i) * 16 + sr) * K + ((t) * 32 + sc),        \
            (void*)(lds + (d) * 16384 + 8192 + w * 1024 + (i) * 512))

  // prologue: stage tiles 0,1,2 into buffers 0,1,2
  const int npro = (NT < 3) ? NT : 3;
  for (int t = 0; t < npro; ++t) {
    STAGE_A(t, t, 0); STAGE_B(t, t, 0);
    STAGE_A(t, t, 1); STAGE_B(t, t, 1);
  }
  if (NT >= 3)      asm volatile("s_waitcnt vmcnt(8)" ::: "memory");
  else if (NT == 2) asm volatile("s_waitcnt vmcnt(4)" ::: "memory");
  else              asm volatile("s_waitcnt vmcnt(0)" ::: "memory");
  __builtin_amdgcn_s_barrier();

  for (int t = 0; t < NT; ++t) {
    const int d  = t & 3;
    const __hip_bfloat16* As = lds + d * 16384;
    const __hip_bfloat16* Bs = As + 8192;
    const int tp = t + 3;
    const int dp = tp & 3;
    const bool pf = tp < NT;

    bf16x8 bfr[4];
    #pragma unroll
    for (int nf = 0; nf < 4; ++nf)
      bfr[nf] = *reinterpret_cast<const bf16x8*>(&Bs[(wn * 64 + nf * 16 + fr) * 32 + kqs]);

    #pragma unroll
    for (int half = 0; half < 2; ++half) {
      if (pf) {
        if (half == 0) { STAGE_A(tp, dp, 0); STAGE_A(tp, dp, 1); }
        else           { STAGE_B(tp, dp, 0); STAGE_B(tp, dp, 1); }
      }
      bf16x8 afr[4];
      #pragma unroll
      for (int q = 0; q < 4; ++q)
        afr[q] = *reinterpret_cast<const bf16x8*>(&As[(wm * 128 + (half * 4 + q) * 16 + fr) * 32 + kqs]);
      __builtin_amdgcn_s_setprio(1);
      #pragma unroll
      for (int q = 0; q < 4; ++q)
        #pragma unroll
        for (int nf = 0; nf < 4; ++nf)
          acc[half * 4 + q][nf] =
              __builtin_amdgcn_mfma_f32_16x16x32_bf16(afr[q], bfr[nf], acc[half * 4 + q][nf], 0, 0, 0);
      __builtin_amdgcn_s_setprio(0);
    }

    // wait tile t+1 landed; keep up to 2 younger tiles in flight (never vmcnt(0) mid-loop)
    if (t + 3 < NT)      asm volatile("s_waitcnt vmcnt(8)" ::: "memory");
    else if (t + 2 < NT) asm volatile("s_waitcnt vmcnt(4)" ::: "memory");
    else if (t + 1 < NT) asm volatile("s_waitcnt vmcnt(0)" ::: "memory");
    if (t + 1 < NT) __builtin_amdgcn_s_barrier();
  }
  #undef STAGE_A
  #undef STAGE_B

  // ---- fused LSTM cell epilogue ----
  const int fq = lane >> 4;
  const int cb = n0 + wn * 64;            // quadrant col base (multiple of 64)
  const int j  = ((cb >> 6) << 4) | fr;   // this lane's hidden index

  const float bs0 = bcomb[cb + fr];
  const float bs1 = bcomb[cb + 16 + fr];
  const float bs2 = bcomb[cb + 32 + fr];
  const float bs3 = bcomb[cb + 48 + fr];

  #pragma unroll
  for (int mf = 0; mf < 8; ++mf) {
    #pragma unroll
    for (int r = 0; r < 4; ++r) {
      const int b = m0 + wm * 128 + mf * 16 + fq * 4 + r;
      float gi = acc[mf][0][r] + bs0;
      float gf = acc[mf][1][r] + bs1;
      float gg = acc[mf][2][r] + bs2;
      float go = acc[mf][3][r] + bs3;
      if (FB) {
        const float* wr = W0T + (size_t)idx[b] * GN;
        gi += wr[cb + fr];
        gf += wr[cb + 16 + fr];
        gg += wr[cb + 32 + fr];
        go += wr[cb + 48 + fr];
      }
      const size_t ci = (size_t)b * HIDDEN + j;
      const float cn = sigm(gf) * c[ci] + sigm(gi) * tanhfast(gg);
      c[ci] = cn;
      const float hn = sigm(go) * tanhfast(cn);
      const __hip_bfloat16 hb = __float2bfloat16(hn);
      h1dst[(size_t)b * ld1 + j] = hb;
      if (h2dst) h2dst[(size_t)b * ld2 + j] = hb;
    }
  }
}

// ---------------------------------------------------------------- logits GEMM (64x128 tile, 128 blocks)
// C(M x 256) = A(M x K) @ W(256 x K)^T. 4 waves (2M x 2N), per-wave 32x64.
// 12 KB LDS -> high occupancy; doubles block parallelism vs 128^2 tile.
__global__ __launch_bounds__(256, 4)
void gemm_bt64_k(const __hip_bfloat16* __restrict__ A, int lda,
                 const __hip_bfloat16* __restrict__ W, int ldw,
                 float* __restrict__ C, int ldc, int K)
{
  __shared__ __align__(16) __hip_bfloat16 As[64 * 32];    // 4 KB
  __shared__ __align__(16) __hip_bfloat16 Bs[128 * 32];   // 8 KB

  const int tid  = threadIdx.x;
  const int w    = tid >> 6;        // wave 0..3
  const int lane = tid & 63;
  const int m0 = blockIdx.y * 64;
  const int n0 = blockIdx.x * 128;
  const int wm = w >> 1;            // 0..1 : 32-row half
  const int wn = w & 1;             // 0..1 : 64-col half
  const int fr = lane & 15;
  const int kqs = (((lane >> 4) ^ ((fr >> 1) & 3)) * 8);   // swizzled read slot
  const int sr  = lane >> 2;
  const int sc  = (((lane & 3) ^ ((sr >> 1) & 3)) * 8);    // pre-swizzled source

  f32x4 acc[2][4] = {};

  for (int k0 = 0; k0 < K; k0 += 32) {
    __syncthreads();
    // A: 4 stripes of 16 rows (one per wave); B: 8 stripes (two per wave)
    g2lds16(A + (size_t)(m0 + w * 16 + sr) * lda + (k0 + sc), (void*)(As + (w * 16) * 32));
    g2lds16(W + (size_t)(n0 + w * 16 + sr) * ldw + (k0 + sc), (void*)(Bs + (w * 16) * 32));
    g2lds16(W + (size_t)(n0 + 64 + w * 16 + sr) * ldw + (k0 + sc), (void*)(Bs + (64 + w * 16) * 32));
    __syncthreads();

    bf16x8 af[2], bw[4];
    #pragma unroll
    for (int i = 0; i < 2; ++i)
      af[i] = *reinterpret_cast<const bf16x8*>(&As[(wm * 32 + i * 16 + fr) * 32 + kqs]);
    #pragma unroll
    for (int j = 0; j < 4; ++j)
      bw[j] = *reinterpret_cast<const bf16x8*>(&Bs[(wn * 64 + j * 16 + fr) * 32 + kqs]);
    #pragma unroll
    for (int i = 0; i < 2; ++i)
      #pragma unroll
      for (int j = 0; j < 4; ++j)
        acc[i][j] = __builtin_amdgcn_mfma_f32_16x16x32_bf16(af[i], bw[j], acc[i][j], 0, 0, 0);
  }

  const int fq = lane >> 4;
  #pragma unroll
  for (int i = 0; i < 2; ++i)
    #pragma unroll
    for (int j = 0; j < 4; ++j)
      #pragma unroll
      for (int r = 0; r < 4; ++r) {
        const int row = m0 + wm * 32 + i * 16 + fq * 4 + r;
        const int col = n0 + wn * 64 + j * 16 + fr;
        C[(size_t)row * ldc + col] = acc[i][j][r];
      }
}

// ---------------------------------------------------------------- log_softmax + argmax + y staging
__global__ void smax_k(const float* __restrict__ LG,   // 4096 x LGN logits (no bias yet)
                       const float* __restrict__ bfv,  // bf (130)
                       float* __restrict__ out, int t,
                       const float* __restrict__ x,
                       __hip_bfloat16* __restrict__ A0next,
                       int* __restrict__ idx)
{
  const int b    = blockIdx.x;
  const int lane = threadIdx.x;   // 64
  const float NINF = -__builtin_inff();
  const float* lg = LG + (size_t)b * LGN;

  const int c1 = lane + 64, c2 = lane + 128;
  float v0 = lg[lane] + bfv[lane];
  float v1 = lg[c1] + bfv[c1];
  float v2 = (c2 < XDIM) ? lg[c2] + bfv[c2] : NINF;

  float m = fmaxf(v0, fmaxf(v1, v2));
  #pragma unroll
  for (int o = 32; o > 0; o >>= 1) m = fmaxf(m, __shfl_xor(m, o, 64));

  int bi = 0x7fffffff;
  if (v0 == m) bi = lane;
  if (v1 == m) bi = min(bi, c1);
  if (v2 == m) bi = min(bi, c2);
  #pragma unroll
  for (int o = 32; o > 0; o >>= 1) bi = min(bi, __shfl_xor(bi, o, 64));

  float s = __expf(v0 - m) + __expf(v1 - m) + ((c2 < XDIM) ? __expf(v2 - m) : 0.f);
  #pragma unroll
  for (int o = 32; o > 0; o >>= 1) s += __shfl_xor(s, o, 64);
  const float lse = __logf(s);

  float* orow = out + ((size_t)b * NSTEP + t) * XDIM;
  orow[lane] = v0 - m - lse;
  orow[c1]   = v1 - m - lse;
  if (c2 < XDIM) orow[c2] = v2 - m - lse;
  if (lane == 0) idx[b] = bi;

  if (t + 1 < NSTEP) {   // stage next step's y (+ zero pad) into A0next cols 1024..1087
    const float yv = (lane < CONDDIM)
        ? x[((size_t)b * NSTEP + (t + 1)) * INDIM + XDIM + lane] : 0.f;
    A0next[(size_t)b * K0P + HIDDEN + lane] = __float2bfloat16(yv);
  }
}

// ---------------------------------------------------------------- init + weight packing
__global__ void init_k(const float* __restrict__ z, const float* __restrict__ x,
                       float* __restrict__ c0, float* __restrict__ c1,
                       __hip_bfloat16* __restrict__ A0, __hip_bfloat16* __restrict__ A1,
                       int* __restrict__ idx)
{
  const int t = blockIdx.x * blockDim.x + threadIdx.x;
  if (t >= BP * K1P) return;
  const int b = t >> 11;
  const int j = t & 2047;
  if (j >= HIDDEN)   // A1 second half: h1(-1) = z
    A1[(size_t)b * K1P + j] = __float2bfloat16(z[(size_t)b * HIDDEN + (j - HIDDEN)]);
  if (j < HIDDEN) {
    c0[(size_t)b * HIDDEN + j] = 0.f;
    c1[(size_t)b * HIDDEN + j] = 0.f;
    A0[(size_t)b * K0P + j] = __float2bfloat16(z[(size_t)b * HIDDEN + j]);  // h0(-1) = z
  } else if (j < HIDDEN + 64) {                     // y_0 + zero pad
    const int k = j - HIDDEN;
    const float yv = (k < CONDDIM) ? x[((size_t)b * NSTEP) * INDIM + XDIM + k] : 0.f;
    A0[(size_t)b * K0P + j] = __float2bfloat16(yv);
  }
  if (j == 0) idx[b] = 1;   // o0 one-hot at index 1
}

__global__ void pack0_k(const float* __restrict__ Wih0, const float* __restrict__ Whh0,
                        const float* __restrict__ bih0, const float* __restrict__ bhh0,
                        __hip_bfloat16* __restrict__ Wc0, float* __restrict__ bc0)
{
  const int t = blockIdx.x * blockDim.x + threadIdx.x;
  if (t >= GN * K0P) return;
  const int n = t / K0P, k = t % K0P;
  const int row = fused_row(n);
  float v = 0.f;
  if (k < HIDDEN)                v = Whh0[(size_t)row * HIDDEN + k];
  else if (k < HIDDEN + CONDDIM) v = Wih0[(size_t)row * INDIM + XDIM + (k - HIDDEN)];
  Wc0[t] = __float2bfloat16(v);
  if (k == 0) bc0[n] = bih0[row] + bhh0[row];
}

__global__ void pack1_k(const float* __restrict__ Wih1, const float* __restrict__ Whh1,
                        const float* __restrict__ bih1, const float* __restrict__ bhh1,
                        __hip_bfloat16* __restrict__ Wc1, float* __restrict__ bc1)
{
  const int t = blockIdx.x * blockDim.x + threadIdx.x;
  if (t >= GN * K1P) return;
  const int n = t >> 11, k = t & 2047;
  const int row = fused_row(n);
  const float v = (k < HIDDEN) ? Wih1[(size_t)row * HIDDEN + k]
                               : Whh1[(size_t)row * HIDDEN + (k - HIDDEN)];
  Wc1[t] = __float2bfloat16(v);
  if (k == 0) bc1[n] = bih1[row] + bhh1[row];
}

__global__ void packf_k(const float* __restrict__ Wf, __hip_bfloat16* __restrict__ Wfp)
{
  const int t = blockIdx.x * blockDim.x + threadIdx.x;
  if (t >= LGN * HIDDEN) return;
  const int r = t >> 10, k = t & 1023;
  const float v = (r < XDIM) ? Wf[(size_t)r * HIDDEN + k] : 0.f;
  Wfp[t] = __float2bfloat16(v);
}

__global__ void packt_k(const float* __restrict__ Wih0, float* __restrict__ W0T)
{
  const int t = blockIdx.x * blockDim.x + threadIdx.x;
  if (t >= XDIM * GN) return;
  const int e = t >> 12, n = t & 4095;      // W0T[e][n] = Wih0[fused_row(n)][e]
  W0T[t] = Wih0[(size_t)fused_row(n) * INDIM + e];
}

// ---------------------------------------------------------------- launch
extern "C" void kernel_launch(void* const* d_in, const int* in_sizes, int n_in,
                              void* d_out, int out_size, void* d_ws, size_t ws_size,
                              hipStream_t stream)
{
  const float* z    = (const float*)d_in[0];
  const float* x    = (const float*)d_in[1];
  const float* Wih0 = (const float*)d_in[2];
  const float* Whh0 = (const float*)d_in[3];
  const float* bih0 = (const float*)d_in[4];
  const float* bhh0 = (const float*)d_in[5];
  const float* Wih1 = (const float*)d_in[6];
  const float* Whh1 = (const float*)d_in[7];
  const float* bih1 = (const float*)d_in[8];
  const float* bhh1 = (const float*)d_in[9];
  const float* Wf   = (const float*)d_in[10];
  const float* bfv  = (const float*)d_in[11];
  float* out = (float*)d_out;

  char* ws = (char*)d_ws;
  size_t off = 0;
  auto alloc = [&](size_t bytes) { void* p = ws + off; off += (bytes + 255) & ~(size_t)255; return p; };

  float*          LG  = (float*)         alloc((size_t)BP * LGN * 4);      // logits
  __hip_bfloat16* A0a = (__hip_bfloat16*)alloc((size_t)BP * K0P * 2);
  __hip_bfloat16* A0b = (__hip_bfloat16*)alloc((size_t)BP * K0P * 2);
  __hip_bfloat16* A1a = (__hip_bfloat16*)alloc((size_t)BP * K1P * 2);
  __hip_bfloat16* A1b = (__hip_bfloat16*)alloc((size_t)BP * K1P * 2);
  __hip_bfloat16* Wc0 = (__hip_bfloat16*)alloc((size_t)GN * K0P * 2);
  __hip_bfloat16* Wc1 = (__hip_bfloat16*)alloc((size_t)GN * K1P * 2);
  __hip_bfloat16* Wfp = (__hip_bfloat16*)alloc((size_t)LGN * HIDDEN * 2);
  float*          W0T = (float*)         alloc((size_t)XDIM * GN * 4);
  float*          bc0 = (float*)         alloc((size_t)GN * 4);
  float*          bc1 = (float*)         alloc((size_t)GN * 4);
  float*          c0  = (float*)         alloc((size_t)BP * HIDDEN * 4);
  float*          c1  = (float*)         alloc((size_t)BP * HIDDEN * 4);
  int*            idx = (int*)           alloc((size_t)BP * 4);
  (void)ws_size; (void)in_sizes; (void)n_in; (void)out_size;

  pack0_k<<<(GN * K0P + 255) / 256, 256, 0, stream>>>(Wih0, Whh0, bih0, bhh0, Wc0, bc0);
  pack1_k<<<(GN * K1P + 255) / 256, 256, 0, stream>>>(Wih1, Whh1, bih1, bhh1, Wc1, bc1);
  packf_k<<<(LGN * HIDDEN + 255) / 256, 256, 0, stream>>>(Wf, Wfp);
  packt_k<<<(XDIM * GN + 255) / 256, 256, 0, stream>>>(Wih0, W0T);
  init_k<<<(BP * K1P + 255) / 256, 256, 0, stream>>>(z, x, c0, c1, A0a, A1a, idx);

  for (int t = 0; t < NSTEP; ++t) {
    __hip_bfloat16* A0c = (t & 1) ? A0b : A0a;
    __hip_bfloat16* A0n = (t & 1) ? A0a : A0b;
    __hip_bfloat16* A1c = (t & 1) ? A1b : A1a;
    __hip_bfloat16* A1n = (t & 1) ? A1a : A1b;

    // layer 0: gates = [h0|y] @ [Whh0|Wih0_y]^T, fused cell -> h0'
    gemm256_cell_k<true><<<256, 512, 0, stream>>>(
        A0c, Wc0, K0P, bc0, W0T, idx, c0,
        A1c, K1P,        // h0' -> A1 (current) first half, read by GEMM1 this step
        A0n, K0P);       // h0' -> A0 (next step)
    // layer 1: gates = [h0'|h1] @ [Wih1|Whh1]^T, fused cell -> h1'
    gemm256_cell_k<false><<<256, 512, 0, stream>>>(
        A1c, Wc1, K1P, bc1, nullptr, nullptr, c1,
        A1n + HIDDEN, K1P,   // h1' -> A1 (next) second half
        nullptr, 0);
    // logits = h1' @ Wf^T  (64x128 tile, 128 blocks)
    gemm_bt64_k<<<dim3(LGN / 128, BP / 64), dim3(256), 0, stream>>>(
        A1n + HIDDEN, K1P, Wfp, HIDDEN, LG, LGN, HIDDEN);
    smax_k<<<BP, 64, 0, stream>>>(LG, bfv, out, t, x, A0n, idx);
  }
}